// Round 1
// baseline (5581.347 us; speedup 1.0000x reference)
//
#include <hip/hip_runtime.h>

#define DIM 2048
#define LEAK 0.2f

typedef __bf16 bf16x8 __attribute__((ext_vector_type(8)));
typedef float  f32x4  __attribute__((ext_vector_type(4)));
typedef unsigned int u32x4 __attribute__((ext_vector_type(4)));

static __device__ __forceinline__ unsigned short f2bf(float f) {
    unsigned int x = __float_as_uint(f);
    return (unsigned short)((x + 0x7fffu + ((x >> 16) & 1u)) >> 16);  // RNE
}
static __device__ __forceinline__ float bf2f(unsigned short h) {
    return __uint_as_float(((unsigned int)h) << 16);
}

static __device__ __forceinline__ void async16(const void* g, void* s) {
    __builtin_amdgcn_global_load_lds(
        (const __attribute__((address_space(1))) void*)g,
        (__attribute__((address_space(3))) void*)s, 16, 0, 0);
}

static __device__ __forceinline__ bf16x8 ld_frag(const unsigned short* p) {
    union { u32x4 u; bf16x8 v; } cv;
    cv.u = *(const u32x4*)p;   // ds_read_b128
    return cv.v;
}

// fp32 -> (hi, lo) bf16 split, no transpose. 4 elems/thread via float4.
__global__ __launch_bounds__(256) void split_kernel(
    const float* __restrict__ in,
    unsigned short* __restrict__ hi, unsigned short* __restrict__ lo) {
    int idx = blockIdx.x * 256 + threadIdx.x;
    float4 v = ((const float4*)in)[idx];
    ushort4 h, l;
    h.x = f2bf(v.x); l.x = f2bf(v.x - bf2f(h.x));
    h.y = f2bf(v.y); l.y = f2bf(v.y - bf2f(h.y));
    h.z = f2bf(v.z); l.z = f2bf(v.z - bf2f(h.z));
    h.w = f2bf(v.w); l.w = f2bf(v.w - bf2f(h.w));
    ((ushort4*)hi)[idx] = h;
    ((ushort4*)lo)[idx] = l;
}

// out[n][k] = in[k][n], fp32 -> bf16 hi (+ optional lo). 32x32 LDS tiles.
__global__ __launch_bounds__(256) void transpose_split(
    const float* __restrict__ in,
    unsigned short* __restrict__ hiT, unsigned short* __restrict__ loT,
    int has_lo) {
    __shared__ float t[32][33];   // +1 pad: conflict-free transpose
    int bx = blockIdx.x, by = blockIdx.y;
    int tx = threadIdx.x & 31, ty4 = (threadIdx.x >> 5) << 2;
#pragma unroll
    for (int i = 0; i < 4; i++)
        t[ty4 + i][tx] = in[(size_t)(by * 32 + ty4 + i) * DIM + bx * 32 + tx];
    __syncthreads();
#pragma unroll
    for (int i = 0; i < 4; i++) {
        float v = t[tx][ty4 + i];
        size_t o = (size_t)(bx * 32 + ty4 + i) * DIM + by * 32 + tx;
        unsigned short h = f2bf(v);
        hiT[o] = h;
        if (has_lo) loT[o] = f2bf(v - bf2f(h));
    }
}

// C[m][n] = (Ahi+Alo)[m][:] dot BT[n][:]  (+ epilogue per MODE)
// MODE 0: Cout = P
// MODE 1: Cout = Cin + P + bias[n]            (drive finalize; in-place safe)
// MODE 2: y = Cin + P; s_old = Ahi+Alo at (m,n);
//         s = 0.8*s_old + 0.2*tanh(y); write split; fp32 out if write_f32
template <int MODE>
__global__ __launch_bounds__(256) void gemm2(
    const unsigned short* __restrict__ Ahi,
    const unsigned short* __restrict__ Alo,
    const unsigned short* __restrict__ BT,
    const float* __restrict__ Cin,
    const float* __restrict__ bias,
    float* __restrict__ Cout,
    unsigned short* __restrict__ Ohi,
    unsigned short* __restrict__ Olo,
    int write_f32) {
    __shared__ alignas(16) unsigned short sAh[128 * 32];
    __shared__ alignas(16) unsigned short sAl[128 * 32];
    __shared__ alignas(16) unsigned short sB [128 * 32];

    // XCD swizzle: bid&7 = XCD (round-robin dispatch); each XCD owns a 4x8
    // region of the 16x16 tile grid -> ~8MB working set per XCD.
    const int bid = blockIdx.x;
    const int xcd = bid & 7, slot = bid >> 3;
    const int trow = ((xcd >> 1) << 2) + (slot >> 3);
    const int tcol = ((xcd & 1) << 3) + (slot & 7);
    const int row0 = trow << 7, col0 = tcol << 7;

    const int tid = threadIdx.x;
    const int lane = tid & 63, wave = tid >> 6;
    const int quad = lane >> 4, l16 = lane & 15;
    const int wm = wave >> 1, wn = wave & 1;

    // staging: tile = 128 rows x 32 cols bf16 = 8KB = 512 x 16B chunks;
    // thread covers chunks tid and tid+256. LDS dst = chunk*16B (lane-ordered,
    // wave-uniform-base + lane*16 as global_load_lds requires).
    const int c0 = tid, c1 = tid + 256;
    const int ar0 = c0 >> 2, ac0 = (c0 & 3) << 3;
    const int ar1 = c1 >> 2, ac1 = (c1 & 3) << 3;
    const size_t gA0 = (size_t)(row0 + ar0) * DIM + ac0;
    const size_t gA1 = (size_t)(row0 + ar1) * DIM + ac1;
    const size_t gB0 = (size_t)(col0 + ar0) * DIM + ac0;
    const size_t gB1 = (size_t)(col0 + ar1) * DIM + ac1;

    f32x4 acc[4][4] = {};

    for (int k0 = 0; k0 < DIM; k0 += 32) {
        async16(Ahi + gA0 + k0, sAh + c0 * 8);
        async16(Ahi + gA1 + k0, sAh + c1 * 8);
        async16(Alo + gA0 + k0, sAl + c0 * 8);
        async16(Alo + gA1 + k0, sAl + c1 * 8);
        async16(BT  + gB0 + k0, sB  + c0 * 8);
        async16(BT  + gB1 + k0, sB  + c1 * 8);
        __syncthreads();

        bf16x8 ah[4], al[4], bv[4];
#pragma unroll
        for (int i = 0; i < 4; i++) {
            const int off = (((i << 4) + l16) << 5) + (quad << 3);
            ah[i] = ld_frag(sAh + (wm << 11) + off);
            al[i] = ld_frag(sAl + (wm << 11) + off);
            bv[i] = ld_frag(sB  + (wn << 11) + off);
        }
#pragma unroll
        for (int i = 0; i < 4; i++)
#pragma unroll
            for (int j = 0; j < 4; j++) {
                acc[i][j] = __builtin_amdgcn_mfma_f32_16x16x32_bf16(ah[i], bv[j], acc[i][j], 0, 0, 0);
                acc[i][j] = __builtin_amdgcn_mfma_f32_16x16x32_bf16(al[i], bv[j], acc[i][j], 0, 0, 0);
            }
        __syncthreads();
    }

    // epilogue: C/D layout col = lane&15, row = quad*4 + reg  [m89/m91]
#pragma unroll
    for (int i = 0; i < 4; i++) {
        const int rb = row0 + (wm << 6) + (i << 4) + (quad << 2);
#pragma unroll
        for (int j = 0; j < 4; j++) {
            const int c = col0 + (wn << 6) + (j << 4) + l16;
#pragma unroll
            for (int g = 0; g < 4; g++) {
                const size_t idx = (size_t)(rb + g) * DIM + c;
                float p = acc[i][j][g];
                if (MODE == 0) {
                    Cout[idx] = p;
                } else if (MODE == 1) {
                    Cout[idx] = Cin[idx] + p + bias[c];
                } else {
                    float y = Cin[idx] + p;
                    float s_old = bf2f(Ahi[idx]) + bf2f(Alo[idx]);
                    float s = (1.0f - LEAK) * s_old + LEAK * tanhf(y);
                    if (write_f32) Cout[idx] = s;
                    unsigned short h = f2bf(s);
                    Ohi[idx] = h;
                    Olo[idx] = f2bf(s - bf2f(h));
                }
            }
        }
    }
}

extern "C" void kernel_launch(void* const* d_in, const int* in_sizes, int n_in,
                              void* d_out, int out_size, void* d_ws, size_t ws_size,
                              hipStream_t stream) {
    const float* x    = (const float*)d_in[0];
    const float* wgt  = (const float*)d_in[1];
    const float* adj  = (const float*)d_in[2];
    const float* bias = (const float*)d_in[3];
    const float* st0  = (const float*)d_in[4];
    float* out = (float*)d_out;

    const size_t NE = (size_t)DIM * DIM;   // 4M elements
    // ws layout (56 MB total): adjT | bufA | bufB | bufC | bufD | drive
    unsigned short* adjT = (unsigned short*)d_ws;   // 8MB bf16 [n][k]
    unsigned short* bufA = adjT + NE;               // 8MB
    unsigned short* bufB = bufA + NE;               // 8MB
    unsigned short* bufC = bufB + NE;               // 8MB
    unsigned short* bufD = bufC + NE;               // 8MB
    float* drive = (float*)(bufD + NE);             // 16MB fp32

    dim3 blk(256);
    // prep: W^T split into (bufC, bufD); x split into (bufA, bufB); adj^T bf16
    transpose_split<<<dim3(64, 64), blk, 0, stream>>>(wgt, bufC, bufD, 1);
    split_kernel<<<dim3(4096), blk, 0, stream>>>(x, bufA, bufB);
    transpose_split<<<dim3(64, 64), blk, 0, stream>>>(adj, adjT, (unsigned short*)0, 0);

    // drive = x @ W_hi ; drive += x @ W_lo + bias
    gemm2<0><<<dim3(256), blk, 0, stream>>>(bufA, bufB, bufC, (const float*)0,
                                            (const float*)0, drive,
                                            (unsigned short*)0, (unsigned short*)0, 0);
    gemm2<1><<<dim3(256), blk, 0, stream>>>(bufA, bufB, bufD, drive, bias, drive,
                                            (unsigned short*)0, (unsigned short*)0, 0);

    // state0 -> split (bufA, bufB); then 64 fused recurrence steps, ping-pong
    split_kernel<<<dim3(4096), blk, 0, stream>>>(st0, bufA, bufB);
    unsigned short* hi_in = bufA; unsigned short* lo_in = bufB;
    unsigned short* hi_out = bufC; unsigned short* lo_out = bufD;
    for (int t = 0; t < 64; t++) {
        gemm2<2><<<dim3(256), blk, 0, stream>>>(hi_in, lo_in, adjT, drive,
                                                (const float*)0, out,
                                                hi_out, lo_out, (t == 63) ? 1 : 0);
        unsigned short* th = hi_in; hi_in = hi_out; hi_out = th;
        unsigned short* tl = lo_in; lo_in = lo_out; lo_out = tl;
    }
}

// Round 2
// 2283.353 us; speedup vs baseline: 2.4444x; 2.4444x over previous
//
#include <hip/hip_runtime.h>

#define DIM 2048
#define LEAK 0.2f

typedef __bf16 bf16x8 __attribute__((ext_vector_type(8)));
typedef float  f32x4  __attribute__((ext_vector_type(4)));
typedef unsigned int u32x4 __attribute__((ext_vector_type(4)));
typedef int    i32x4  __attribute__((ext_vector_type(4)));

static __device__ __forceinline__ unsigned short f2bf(float f) {
    unsigned int x = __float_as_uint(f);
    return (unsigned short)((x + 0x7fffu + ((x >> 16) & 1u)) >> 16);  // RNE
}
static __device__ __forceinline__ float bf2f(unsigned short h) {
    return __uint_as_float(((unsigned int)h) << 16);
}

static __device__ __forceinline__ void async16(const void* g, void* s) {
    __builtin_amdgcn_global_load_lds(
        (const __attribute__((address_space(1))) void*)g,
        (__attribute__((address_space(3))) void*)s, 16, 0, 0);
}

static __device__ __forceinline__ bf16x8 ld_frag(const unsigned short* p) {
    union { u32x4 u; bf16x8 v; } cv;
    cv.u = *(const u32x4*)p;   // ds_read_b128
    return cv.v;
}

// ---------------- prep kernels ----------------

// fp32 -> (hi, lo) bf16 split (for the drive GEMM inputs).
__global__ __launch_bounds__(256) void split_kernel(
    const float* __restrict__ in,
    unsigned short* __restrict__ hi, unsigned short* __restrict__ lo) {
    int idx = blockIdx.x * 256 + threadIdx.x;
    float4 v = ((const float4*)in)[idx];
    ushort4 h, l;
    h.x = f2bf(v.x); l.x = f2bf(v.x - bf2f(h.x));
    h.y = f2bf(v.y); l.y = f2bf(v.y - bf2f(h.y));
    h.z = f2bf(v.z); l.z = f2bf(v.z - bf2f(h.z));
    h.w = f2bf(v.w); l.w = f2bf(v.w - bf2f(h.w));
    ((ushort4*)hi)[idx] = h;
    ((ushort4*)lo)[idx] = l;
}

// out[n][k] = in[k][n], fp32 -> bf16 hi/lo (W^T for drive GEMM).
__global__ __launch_bounds__(256) void transpose_split(
    const float* __restrict__ in,
    unsigned short* __restrict__ hiT, unsigned short* __restrict__ loT) {
    __shared__ float t[32][33];
    int bx = blockIdx.x, by = blockIdx.y;
    int tx = threadIdx.x & 31, ty4 = (threadIdx.x >> 5) << 2;
#pragma unroll
    for (int i = 0; i < 4; i++)
        t[ty4 + i][tx] = in[(size_t)(by * 32 + ty4 + i) * DIM + bx * 32 + tx];
    __syncthreads();
#pragma unroll
    for (int i = 0; i < 4; i++) {
        float v = t[tx][ty4 + i];
        size_t o = (size_t)(bx * 32 + ty4 + i) * DIM + by * 32 + tx;
        unsigned short h = f2bf(v);
        hiT[o] = h;
        loT[o] = f2bf(v - bf2f(h));
    }
}

// out[n][k] = (int8)in[k][n]  (adjacency is exactly {0,1}).
__global__ __launch_bounds__(256) void transpose_i8(
    const float* __restrict__ in, signed char* __restrict__ outT) {
    __shared__ float t[32][33];
    int bx = blockIdx.x, by = blockIdx.y;
    int tx = threadIdx.x & 31, ty4 = (threadIdx.x >> 5) << 2;
#pragma unroll
    for (int i = 0; i < 4; i++)
        t[ty4 + i][tx] = in[(size_t)(by * 32 + ty4 + i) * DIM + bx * 32 + tx];
    __syncthreads();
#pragma unroll
    for (int i = 0; i < 4; i++)
        outT[(size_t)(bx * 32 + ty4 + i) * DIM + by * 32 + tx] =
            (signed char)t[tx][ty4 + i];
}

// fp32 state -> int15 split: v = clamp(round(s*2^14)); h = v>>7, l = v&127.
__global__ __launch_bounds__(256) void quant_split(
    const float* __restrict__ in,
    signed char* __restrict__ hi, signed char* __restrict__ lo) {
    int idx = blockIdx.x * 256 + threadIdx.x;
    float4 v = ((const float4*)in)[idx];
    char4 h, l;
    {
        int q = (int)rintf(v.x * 16384.f); q = q > 16383 ? 16383 : (q < -16383 ? -16383 : q);
        h.x = (signed char)(q >> 7); l.x = (signed char)(q & 127);
    }
    {
        int q = (int)rintf(v.y * 16384.f); q = q > 16383 ? 16383 : (q < -16383 ? -16383 : q);
        h.y = (signed char)(q >> 7); l.y = (signed char)(q & 127);
    }
    {
        int q = (int)rintf(v.z * 16384.f); q = q > 16383 ? 16383 : (q < -16383 ? -16383 : q);
        h.z = (signed char)(q >> 7); l.z = (signed char)(q & 127);
    }
    {
        int q = (int)rintf(v.w * 16384.f); q = q > 16383 ? 16383 : (q < -16383 ? -16383 : q);
        h.w = (signed char)(q >> 7); l.w = (signed char)(q & 127);
    }
    ((char4*)hi)[idx] = h;
    ((char4*)lo)[idx] = l;
}

// ---------------- bf16 dual GEMM (drive only; proven in R1) ----------------
// MODE 0: Cout = (Ahi+Alo) @ BT^T
// MODE 1: Cout = Cin + P + bias[n]
template <int MODE>
__global__ __launch_bounds__(256) void gemm2(
    const unsigned short* __restrict__ Ahi,
    const unsigned short* __restrict__ Alo,
    const unsigned short* __restrict__ BT,
    const float* __restrict__ Cin,
    const float* __restrict__ bias,
    float* __restrict__ Cout) {
    __shared__ alignas(16) unsigned short sAh[128 * 32];
    __shared__ alignas(16) unsigned short sAl[128 * 32];
    __shared__ alignas(16) unsigned short sB [128 * 32];

    const int bid = blockIdx.x;
    const int xcd = bid & 7, slot = bid >> 3;
    const int trow = ((xcd >> 1) << 2) + (slot >> 3);
    const int tcol = ((xcd & 1) << 3) + (slot & 7);
    const int row0 = trow << 7, col0 = tcol << 7;

    const int tid = threadIdx.x;
    const int lane = tid & 63, wave = tid >> 6;
    const int quad = lane >> 4, l16 = lane & 15;
    const int wm = wave >> 1, wn = wave & 1;

    const int c0 = tid, c1 = tid + 256;
    const int ar0 = c0 >> 2, ac0 = (c0 & 3) << 3;
    const int ar1 = c1 >> 2, ac1 = (c1 & 3) << 3;
    const size_t gA0 = (size_t)(row0 + ar0) * DIM + ac0;
    const size_t gA1 = (size_t)(row0 + ar1) * DIM + ac1;
    const size_t gB0 = (size_t)(col0 + ar0) * DIM + ac0;
    const size_t gB1 = (size_t)(col0 + ar1) * DIM + ac1;

    f32x4 acc[4][4] = {};

    for (int k0 = 0; k0 < DIM; k0 += 32) {
        async16(Ahi + gA0 + k0, sAh + c0 * 8);
        async16(Ahi + gA1 + k0, sAh + c1 * 8);
        async16(Alo + gA0 + k0, sAl + c0 * 8);
        async16(Alo + gA1 + k0, sAl + c1 * 8);
        async16(BT  + gB0 + k0, sB  + c0 * 8);
        async16(BT  + gB1 + k0, sB  + c1 * 8);
        __syncthreads();

        bf16x8 ah[4], al[4], bv[4];
#pragma unroll
        for (int i = 0; i < 4; i++) {
            const int off = (((i << 4) + l16) << 5) + (quad << 3);
            ah[i] = ld_frag(sAh + (wm << 11) + off);
            al[i] = ld_frag(sAl + (wm << 11) + off);
            bv[i] = ld_frag(sB  + (wn << 11) + off);
        }
#pragma unroll
        for (int i = 0; i < 4; i++)
#pragma unroll
            for (int j = 0; j < 4; j++) {
                acc[i][j] = __builtin_amdgcn_mfma_f32_16x16x32_bf16(ah[i], bv[j], acc[i][j], 0, 0, 0);
                acc[i][j] = __builtin_amdgcn_mfma_f32_16x16x32_bf16(al[i], bv[j], acc[i][j], 0, 0, 0);
            }
        __syncthreads();
    }

#pragma unroll
    for (int i = 0; i < 4; i++) {
        const int rb = row0 + (wm << 6) + (i << 4) + (quad << 2);
#pragma unroll
        for (int j = 0; j < 4; j++) {
            const int c = col0 + (wn << 6) + (j << 4) + l16;
#pragma unroll
            for (int g = 0; g < 4; g++) {
                const size_t idx = (size_t)(rb + g) * DIM + c;
                float p = acc[i][j][g];
                if (MODE == 0) Cout[idx] = p;
                else           Cout[idx] = Cin[idx] + p + bias[c];
            }
        }
    }
}

// ---------------- i8 recurrence step ----------------
// y = drive + (Ah*128 + Al) @ A_adj / 2^14 ; s = 0.8*s_old + 0.2*tanh(y)
// Tile 64(m) x 128(n), grid 512 (2 blocks/CU), 4 waves in 2x2, wave-tile 32x64.
// K=64 per iter via v_mfma_i32_16x16x64_i8 (A-frag: 16 k-bytes/lane at quad*16).
// A staged interleaved hi|lo per row (128B stride) with XOR chunk swizzle
// slot = cc ^ (r&7) so ds_read_b128 frag loads stay 2-way (free) on banks.
__global__ __launch_bounds__(256, 2) void step_i8(
    const signed char* __restrict__ Ah,
    const signed char* __restrict__ Al,
    const signed char* __restrict__ BT,
    const float* __restrict__ drive,
    float* __restrict__ out,
    signed char* __restrict__ Oh,
    signed char* __restrict__ Ol,
    int write_f32) {
    __shared__ alignas(16) signed char sA[128 * 128];  // 64 rows x (hi 64B | lo 64B), swizzled
    __shared__ alignas(16) signed char sB[128 * 64];   // 128 rows x 64B

    const int bid = blockIdx.x;
    const int xcd = bid & 7, slot = bid >> 3;            // 64 slots per XCD
    const int tm = ((xcd >> 1) << 3) + (slot >> 3);      // 0..31
    const int tn = ((xcd & 1) << 3) + (slot & 7);        // 0..15
    const int row0 = tm << 6, col0 = tn << 7;

    const int tid = threadIdx.x;
    const int lane = tid & 63;
    const int quad = lane >> 4, l16 = lane & 15;
    const int wave = tid >> 6;
    const int wm = wave >> 1, wn = wave & 1;

    // A staging: 64 rows x 8 chunks (cc = part*4 + kc) = 512 slots... tile is
    // 64 rows -> sA holds 64*128B = 8KB? No: 64 rows x (64+64)B = 8KB... we use
    // 128-slot rows: slots s = r*8 + sc, r in 0..63, total 512 slots -> 2/thread.
    int a_r[2]; const signed char* a_base[2]; int a_dst[2];
#pragma unroll
    for (int i = 0; i < 2; i++) {
        int s = tid + 256 * i;          // 0..511
        int r = s >> 3, sc = s & 7;
        int cc = sc ^ (r & 7);
        int part = cc >> 2, kc = cc & 3;
        a_r[i] = r;
        a_base[i] = (part ? Al : Ah) + (size_t)(row0 + r) * DIM + kc * 16;
        a_dst[i] = s * 16;
    }
    // B staging: 128 rows x 4 chunks = 512 slots -> 2/thread, no swizzle.
    const signed char* b_base[2]; int b_dst[2];
#pragma unroll
    for (int i = 0; i < 2; i++) {
        int s = tid + 256 * i;
        int r = s >> 2, kc = s & 3;
        b_base[i] = BT + (size_t)(col0 + r) * DIM + kc * 16;
        b_dst[i] = s * 16;
    }

    i32x4 acch[2][4] = {};
    i32x4 accl[2][4] = {};

    for (int k0 = 0; k0 < DIM; k0 += 64) {
        async16(a_base[0] + k0, sA + a_dst[0]);
        async16(a_base[1] + k0, sA + a_dst[1]);
        async16(b_base[0] + k0, sB + b_dst[0]);
        async16(b_base[1] + k0, sB + b_dst[1]);
        __syncthreads();

        i32x4 ahf[2], alf[2], bvf[4];
#pragma unroll
        for (int i = 0; i < 2; i++) {
            const int r = (wm << 5) + (i << 4) + l16;        // 0..63
            const int rb = r << 7;                            // *128
            ahf[i] = *(const i32x4*)(sA + rb + ((quad    ) ^ (r & 7)) * 16);
            alf[i] = *(const i32x4*)(sA + rb + ((quad + 4) ^ (r & 7)) * 16);
        }
#pragma unroll
        for (int j = 0; j < 4; j++) {
            const int r = (wn << 6) + (j << 4) + l16;        // 0..127
            bvf[j] = *(const i32x4*)(sB + (r << 6) + (quad << 4));
        }
#pragma unroll
        for (int i = 0; i < 2; i++)
#pragma unroll
            for (int j = 0; j < 4; j++) {
                acch[i][j] = __builtin_amdgcn_mfma_i32_16x16x64_i8(ahf[i], bvf[j], acch[i][j], 0, 0, 0);
                accl[i][j] = __builtin_amdgcn_mfma_i32_16x16x64_i8(alf[i], bvf[j], accl[i][j], 0, 0, 0);
            }
        __syncthreads();
    }

    // C/D layout: col = lane&15, row = quad*4 + g  (shape-determined, m89/m101)
#pragma unroll
    for (int i = 0; i < 2; i++) {
        const int rb = row0 + (wm << 5) + (i << 4) + (quad << 2);
#pragma unroll
        for (int j = 0; j < 4; j++) {
            const int c = col0 + (wn << 6) + (j << 4) + l16;
#pragma unroll
            for (int g = 0; g < 4; g++) {
                const size_t idx = (size_t)(rb + g) * DIM + c;
                int prod = acch[i][j][g] * 128 + accl[i][j][g];     // exact int
                float y = drive[idx] + (float)prod * (1.0f / 16384.0f);
                float sold = (float)((int)Ah[idx] * 128 + (int)Al[idx]) * (1.0f / 16384.0f);
                float s = (1.0f - LEAK) * sold + LEAK * tanhf(y);
                if (write_f32) out[idx] = s;
                int q = (int)rintf(s * 16384.f);
                q = q > 16383 ? 16383 : (q < -16383 ? -16383 : q);
                Oh[idx] = (signed char)(q >> 7);
                Ol[idx] = (signed char)(q & 127);
            }
        }
    }
}

extern "C" void kernel_launch(void* const* d_in, const int* in_sizes, int n_in,
                              void* d_out, int out_size, void* d_ws, size_t ws_size,
                              hipStream_t stream) {
    const float* x    = (const float*)d_in[0];
    const float* wgt  = (const float*)d_in[1];
    const float* adj  = (const float*)d_in[2];
    const float* bias = (const float*)d_in[3];
    const float* st0  = (const float*)d_in[4];
    float* out = (float*)d_out;

    const size_t NE = (size_t)DIM * DIM;
    // ws (52 MB): adjT_i8(4) | drive(16) | bufA..bufD bf16(32); i8 state (16MB)
    // aliases bufA+bufB after the drive GEMMs retire (stream-ordered).
    signed char* adjT = (signed char*)d_ws;
    float* drive = (float*)(adjT + NE);
    unsigned short* bufA = (unsigned short*)(drive + NE);
    unsigned short* bufB = bufA + NE;
    unsigned short* bufC = bufB + NE;
    unsigned short* bufD = bufC + NE;
    signed char* h1 = (signed char*)bufA;
    signed char* l1 = h1 + NE;
    signed char* h2 = l1 + NE;
    signed char* l2 = h2 + NE;

    dim3 blk(256);
    transpose_split<<<dim3(64, 64), blk, 0, stream>>>(wgt, bufC, bufD);
    split_kernel<<<dim3(4096), blk, 0, stream>>>(x, bufA, bufB);
    transpose_i8<<<dim3(64, 64), blk, 0, stream>>>(adj, adjT);

    gemm2<0><<<dim3(256), blk, 0, stream>>>(bufA, bufB, bufC, (const float*)0,
                                            (const float*)0, drive);
    gemm2<1><<<dim3(256), blk, 0, stream>>>(bufA, bufB, bufD, drive, bias, drive);

    // state0 -> int15 split (aliases bufA/bufB region; drive GEMMs are done)
    quant_split<<<dim3(4096), blk, 0, stream>>>(st0, h1, l1);

    signed char* hi = h1; signed char* li = l1;
    signed char* ho = h2; signed char* lo = l2;
    for (int t = 0; t < 64; t++) {
        step_i8<<<dim3(512), blk, 0, stream>>>(hi, li, adjT, drive, out,
                                               ho, lo, (t == 63) ? 1 : 0);
        signed char* th = hi; hi = ho; ho = th;
        signed char* tl = li; li = lo; lo = tl;
    }
}

// Round 3
// 2129.048 us; speedup vs baseline: 2.6215x; 1.0725x over previous
//
#include <hip/hip_runtime.h>

#define DIM 2048
#define LEAK 0.2f

typedef __bf16 bf16x8 __attribute__((ext_vector_type(8)));
typedef float  f32x4  __attribute__((ext_vector_type(4)));
typedef unsigned int u32x4 __attribute__((ext_vector_type(4)));
typedef int    i32x4  __attribute__((ext_vector_type(4)));

static __device__ __forceinline__ unsigned short f2bf(float f) {
    unsigned int x = __float_as_uint(f);
    return (unsigned short)((x + 0x7fffu + ((x >> 16) & 1u)) >> 16);  // RNE
}
static __device__ __forceinline__ float bf2f(unsigned short h) {
    return __uint_as_float(((unsigned int)h) << 16);
}

static __device__ __forceinline__ void async16(const void* g, void* s) {
    __builtin_amdgcn_global_load_lds(
        (const __attribute__((address_space(1))) void*)g,
        (__attribute__((address_space(3))) void*)s, 16, 0, 0);
}

static __device__ __forceinline__ bf16x8 ld_bf16_frag(const char* p) {
    union { u32x4 u; bf16x8 v; } cv;
    cv.u = *(const u32x4*)p;   // ds_read_b128
    return cv.v;
}

// ---------------- prep kernels ----------------

__global__ __launch_bounds__(256) void split_kernel(
    const float* __restrict__ in,
    unsigned short* __restrict__ hi, unsigned short* __restrict__ lo) {
    int idx = blockIdx.x * 256 + threadIdx.x;
    float4 v = ((const float4*)in)[idx];
    ushort4 h, l;
    h.x = f2bf(v.x); l.x = f2bf(v.x - bf2f(h.x));
    h.y = f2bf(v.y); l.y = f2bf(v.y - bf2f(h.y));
    h.z = f2bf(v.z); l.z = f2bf(v.z - bf2f(h.z));
    h.w = f2bf(v.w); l.w = f2bf(v.w - bf2f(h.w));
    ((ushort4*)hi)[idx] = h;
    ((ushort4*)lo)[idx] = l;
}

__global__ __launch_bounds__(256) void transpose_split(
    const float* __restrict__ in,
    unsigned short* __restrict__ hiT, unsigned short* __restrict__ loT) {
    __shared__ float t[32][33];
    int bx = blockIdx.x, by = blockIdx.y;
    int tx = threadIdx.x & 31, ty4 = (threadIdx.x >> 5) << 2;
#pragma unroll
    for (int i = 0; i < 4; i++)
        t[ty4 + i][tx] = in[(size_t)(by * 32 + ty4 + i) * DIM + bx * 32 + tx];
    __syncthreads();
#pragma unroll
    for (int i = 0; i < 4; i++) {
        float v = t[tx][ty4 + i];
        size_t o = (size_t)(bx * 32 + ty4 + i) * DIM + by * 32 + tx;
        unsigned short h = f2bf(v);
        hiT[o] = h;
        loT[o] = f2bf(v - bf2f(h));
    }
}

__global__ __launch_bounds__(256) void transpose_i8(
    const float* __restrict__ in, signed char* __restrict__ outT) {
    __shared__ float t[32][33];
    int bx = blockIdx.x, by = blockIdx.y;
    int tx = threadIdx.x & 31, ty4 = (threadIdx.x >> 5) << 2;
#pragma unroll
    for (int i = 0; i < 4; i++)
        t[ty4 + i][tx] = in[(size_t)(by * 32 + ty4 + i) * DIM + bx * 32 + tx];
    __syncthreads();
#pragma unroll
    for (int i = 0; i < 4; i++)
        outT[(size_t)(bx * 32 + ty4 + i) * DIM + by * 32 + tx] =
            (signed char)t[tx][ty4 + i];
}

__global__ __launch_bounds__(256) void quant_split(
    const float* __restrict__ in,
    signed char* __restrict__ hi, signed char* __restrict__ lo) {
    int idx = blockIdx.x * 256 + threadIdx.x;
    float4 v = ((const float4*)in)[idx];
    char4 h, l;
    {
        int q = (int)rintf(v.x * 16384.f); q = q > 16383 ? 16383 : (q < -16383 ? -16383 : q);
        h.x = (signed char)(q >> 7); l.x = (signed char)(q & 127);
    }
    {
        int q = (int)rintf(v.y * 16384.f); q = q > 16383 ? 16383 : (q < -16383 ? -16383 : q);
        h.y = (signed char)(q >> 7); l.y = (signed char)(q & 127);
    }
    {
        int q = (int)rintf(v.z * 16384.f); q = q > 16383 ? 16383 : (q < -16383 ? -16383 : q);
        h.z = (signed char)(q >> 7); l.z = (signed char)(q & 127);
    }
    {
        int q = (int)rintf(v.w * 16384.f); q = q > 16383 ? 16383 : (q < -16383 ? -16383 : q);
        h.w = (signed char)(q >> 7); l.w = (signed char)(q & 127);
    }
    ((char4*)hi)[idx] = h;
    ((char4*)lo)[idx] = l;
}

// ---------------- bf16 dual-A GEMM (drive), tile 64x128, dbuf ----------------
// MODE 0: Cout = (Ahi+Alo) @ B^T        MODE 1: Cout = Cin + P + bias[n]
// LDS rows: sA 64 x 256B (chunks 0-7 hi | 8-15 lo), sB 128 x 128B.
// XOR chunk swizzle c^(r&7): row strides 256/128B would otherwise put all
// lanes on 4 banks (8-way); swizzled -> uniform 8 dwords/bank (free).
template <int MODE>
__global__ __launch_bounds__(256) void gemm_bf16(
    const unsigned short* __restrict__ Ahi,
    const unsigned short* __restrict__ Alo,
    const unsigned short* __restrict__ BT,
    const float* __restrict__ Cin,
    const float* __restrict__ bias,
    float* __restrict__ Cout) {
    __shared__ alignas(16) char sA[2][16384];
    __shared__ alignas(16) char sB[2][16384];

    const int bid = blockIdx.x;
    const int xcd = bid & 7, slot = bid >> 3;
    const int tm = ((xcd >> 1) << 3) + (slot >> 3);      // 0..31
    const int tn = ((xcd & 1) << 3) + (slot & 7);        // 0..15
    const int row0 = tm << 6, col0 = tn << 7;

    const int tid = threadIdx.x;
    const int lane = tid & 63;
    const int quad = lane >> 4, l16 = lane & 15;
    const int wave = tid >> 6;
    const int wm = wave >> 1, wn = wave & 1;

    const unsigned short* a_src[4]; int a_dst[4];
    const unsigned short* b_src[4]; int b_dst[4];
#pragma unroll
    for (int i = 0; i < 4; i++) {
        int s = tid + 256 * i;                 // 0..1023
        { // A: r = s>>4 (64 rows), group g = (s>>3)&1, chunk c = (s&7)^(r&7), 8 elems/chunk
            int r = s >> 4, g = (s >> 3) & 1, c = (s & 7) ^ (r & 7);
            a_src[i] = (g ? Alo : Ahi) + (size_t)(row0 + r) * DIM + c * 8;
            a_dst[i] = s * 16;
        }
        { // B: r = s>>3 (128 rows), chunk c = (s&7)^(r&7)
            int r = s >> 3, c = (s & 7) ^ (r & 7);
            b_src[i] = BT + (size_t)(col0 + r) * DIM + c * 8;
            b_dst[i] = s * 16;
        }
    }

    f32x4 acc[2][4] = {};

    auto stage = [&](int p, int k0) {
#pragma unroll
        for (int i = 0; i < 4; i++) {
            async16(a_src[i] + k0, sA[p] + a_dst[i]);
            async16(b_src[i] + k0, sB[p] + b_dst[i]);
        }
    };

    stage(0, 0);
    __syncthreads();
    for (int it = 0; it < 32; it++) {          // BK = 64 elems (128B)
        const int p = it & 1;
        if (it + 1 < 32) stage(1 - p, (it + 1) * 64);
#pragma unroll
        for (int kk = 0; kk < 2; kk++) {       // two K=32 MFMA phases
            bf16x8 ah[2], al[2], bv[4];
#pragma unroll
            for (int i = 0; i < 2; i++) {
                const int r = (wm << 5) + (i << 4) + l16;
                const int cs = ((kk << 2) + quad) ^ (r & 7);
                ah[i] = ld_bf16_frag(sA[p] + ((r << 4) + cs) * 16);
                al[i] = ld_bf16_frag(sA[p] + ((r << 4) + 8 + cs) * 16);
            }
#pragma unroll
            for (int j = 0; j < 4; j++) {
                const int r = (wn << 6) + (j << 4) + l16;
                const int cs = ((kk << 2) + quad) ^ (r & 7);
                bv[j] = ld_bf16_frag(sB[p] + ((r << 3) + cs) * 16);
            }
#pragma unroll
            for (int i = 0; i < 2; i++)
#pragma unroll
                for (int j = 0; j < 4; j++) {
                    acc[i][j] = __builtin_amdgcn_mfma_f32_16x16x32_bf16(ah[i], bv[j], acc[i][j], 0, 0, 0);
                    acc[i][j] = __builtin_amdgcn_mfma_f32_16x16x32_bf16(al[i], bv[j], acc[i][j], 0, 0, 0);
                }
        }
        __syncthreads();
    }

#pragma unroll
    for (int i = 0; i < 2; i++) {
        const int rb = row0 + (wm << 5) + (i << 4) + (quad << 2);
#pragma unroll
        for (int j = 0; j < 4; j++) {
            const int c = col0 + (wn << 6) + (j << 4) + l16;
#pragma unroll
            for (int g = 0; g < 4; g++) {
                const size_t idx = (size_t)(rb + g) * DIM + c;
                if (MODE == 0) Cout[idx] = acc[i][j][g];
                else           Cout[idx] = Cin[idx] + acc[i][j][g] + bias[c];
            }
        }
    }
}

// ---------------- i8 recurrence step, tile 64x128, BK=128B, dbuf ----------------
// y = drive + ((Ah*128+Al) @ adjT^T)/2^14 ; s = 0.8*s_old + 0.2*tanh(y)
__global__ __launch_bounds__(256) void step_i8(
    const signed char* __restrict__ Ah,
    const signed char* __restrict__ Al,
    const signed char* __restrict__ BT,
    const float* __restrict__ drive,
    float* __restrict__ out,
    signed char* __restrict__ Oh,
    signed char* __restrict__ Ol,
    int write_f32) {
    __shared__ alignas(16) char sA[2][16384];  // 64 rows x 256B (hi 0-7 | lo 8-15), swizzled
    __shared__ alignas(16) char sB[2][16384];  // 128 rows x 128B, swizzled

    const int bid = blockIdx.x;
    const int xcd = bid & 7, slot = bid >> 3;
    const int tm = ((xcd >> 1) << 3) + (slot >> 3);
    const int tn = ((xcd & 1) << 3) + (slot & 7);
    const int row0 = tm << 6, col0 = tn << 7;

    const int tid = threadIdx.x;
    const int lane = tid & 63;
    const int quad = lane >> 4, l16 = lane & 15;
    const int wave = tid >> 6;
    const int wm = wave >> 1, wn = wave & 1;

    const signed char* a_src[4]; int a_dst[4];
    const signed char* b_src[4]; int b_dst[4];
#pragma unroll
    for (int i = 0; i < 4; i++) {
        int s = tid + 256 * i;
        {
            int r = s >> 4, g = (s >> 3) & 1, c = (s & 7) ^ (r & 7);
            a_src[i] = (g ? Al : Ah) + (size_t)(row0 + r) * DIM + c * 16;
            a_dst[i] = s * 16;
        }
        {
            int r = s >> 3, c = (s & 7) ^ (r & 7);
            b_src[i] = BT + (size_t)(col0 + r) * DIM + c * 16;
            b_dst[i] = s * 16;
        }
    }

    i32x4 acch[2][4] = {};
    i32x4 accl[2][4] = {};

    auto stage = [&](int p, int k0) {
#pragma unroll
        for (int i = 0; i < 4; i++) {
            async16(a_src[i] + k0, sA[p] + a_dst[i]);
            async16(b_src[i] + k0, sB[p] + b_dst[i]);
        }
    };

    stage(0, 0);
    __syncthreads();
    for (int it = 0; it < 16; it++) {          // BK = 128 bytes of k
        const int p = it & 1;
        if (it + 1 < 16) stage(1 - p, (it + 1) * 128);
#pragma unroll
        for (int kk = 0; kk < 2; kk++) {       // two K=64 MFMA phases
            i32x4 ahf[2], alf[2], bvf[4];
#pragma unroll
            for (int i = 0; i < 2; i++) {
                const int r = (wm << 5) + (i << 4) + l16;
                const int cs = ((kk << 2) + quad) ^ (r & 7);
                ahf[i] = *(const i32x4*)(sA[p] + ((r << 4) + cs) * 16);
                alf[i] = *(const i32x4*)(sA[p] + ((r << 4) + 8 + cs) * 16);
            }
#pragma unroll
            for (int j = 0; j < 4; j++) {
                const int r = (wn << 6) + (j << 4) + l16;
                const int cs = ((kk << 2) + quad) ^ (r & 7);
                bvf[j] = *(const i32x4*)(sB[p] + ((r << 3) + cs) * 16);
            }
#pragma unroll
            for (int i = 0; i < 2; i++)
#pragma unroll
                for (int j = 0; j < 4; j++) {
                    acch[i][j] = __builtin_amdgcn_mfma_i32_16x16x64_i8(ahf[i], bvf[j], acch[i][j], 0, 0, 0);
                    accl[i][j] = __builtin_amdgcn_mfma_i32_16x16x64_i8(alf[i], bvf[j], accl[i][j], 0, 0, 0);
                }
        }
        __syncthreads();
    }

#pragma unroll
    for (int i = 0; i < 2; i++) {
        const int rb = row0 + (wm << 5) + (i << 4) + (quad << 2);
#pragma unroll
        for (int j = 0; j < 4; j++) {
            const int c = col0 + (wn << 6) + (j << 4) + l16;
#pragma unroll
            for (int g = 0; g < 4; g++) {
                const size_t idx = (size_t)(rb + g) * DIM + c;
                int prod = acch[i][j][g] * 128 + accl[i][j][g];   // exact int
                float y = drive[idx] + (float)prod * (1.0f / 16384.0f);
                float sold = (float)((int)Ah[idx] * 128 + (int)Al[idx]) * (1.0f / 16384.0f);
                // tanh(y) = 1 - 2/(exp(2y)+1); exp inf/0 saturate correctly
                float e = __expf(2.0f * y);
                float th = 1.0f - 2.0f / (e + 1.0f);
                float s = (1.0f - LEAK) * sold + LEAK * th;
                if (write_f32) out[idx] = s;
                int q = (int)rintf(s * 16384.f);
                q = q > 16383 ? 16383 : (q < -16383 ? -16383 : q);
                Oh[idx] = (signed char)(q >> 7);
                Ol[idx] = (signed char)(q & 127);
            }
        }
    }
}

extern "C" void kernel_launch(void* const* d_in, const int* in_sizes, int n_in,
                              void* d_out, int out_size, void* d_ws, size_t ws_size,
                              hipStream_t stream) {
    const float* x    = (const float*)d_in[0];
    const float* wgt  = (const float*)d_in[1];
    const float* adj  = (const float*)d_in[2];
    const float* bias = (const float*)d_in[3];
    const float* st0  = (const float*)d_in[4];
    float* out = (float*)d_out;

    const size_t NE = (size_t)DIM * DIM;
    // ws (52 MB): adjT_i8(4) | drive(16) | bufA..bufD bf16(32);
    // i8 state ping-pong (4x4MB) aliases bufA/bufB after drive GEMMs retire.
    signed char* adjT = (signed char*)d_ws;
    float* drive = (float*)(adjT + NE);
    unsigned short* bufA = (unsigned short*)(drive + NE);
    unsigned short* bufB = bufA + NE;
    unsigned short* bufC = bufB + NE;
    unsigned short* bufD = bufC + NE;
    signed char* h1 = (signed char*)bufA;
    signed char* l1 = h1 + NE;
    signed char* h2 = l1 + NE;
    signed char* l2 = h2 + NE;

    dim3 blk(256);
    transpose_split<<<dim3(64, 64), blk, 0, stream>>>(wgt, bufC, bufD);
    split_kernel<<<dim3(4096), blk, 0, stream>>>(x, bufA, bufB);
    transpose_i8<<<dim3(64, 64), blk, 0, stream>>>(adj, adjT);

    gemm_bf16<0><<<dim3(512), blk, 0, stream>>>(bufA, bufB, bufC, (const float*)0,
                                                (const float*)0, drive);
    gemm_bf16<1><<<dim3(512), blk, 0, stream>>>(bufA, bufB, bufD, drive, bias, drive);

    quant_split<<<dim3(4096), blk, 0, stream>>>(st0, h1, l1);

    signed char* hi = h1; signed char* li = l1;
    signed char* ho = h2; signed char* lo = l2;
    for (int t = 0; t < 64; t++) {
        step_i8<<<dim3(512), blk, 0, stream>>>(hi, li, adjT, drive, out,
                                               ho, lo, (t == 63) ? 1 : 0);
        signed char* th = hi; hi = ho; ho = th;
        signed char* tl = li; li = lo; lo = tl;
    }
}